// Round 4
// baseline (685.003 us; speedup 1.0000x reference)
//
#include <hip/hip_runtime.h>
#include <hip/hip_bf16.h>
#include <math.h>

// Problem constants
#define B_  4
#define L_  384
#define DS_ 384
#define DP_ 128
#define NB_ 4
#define FEAT_ (DS_ + 2*DP_)   // 640
#define LN_EPS_ 1e-5f
#define T_ 16
#define NT_ (L_ / T_)              // 24 tiles
#define NTP_ (NT_ * (NT_ + 1) / 2) // 300 tile-pairs (ta<=tb)
#define NCH_ 8                     // reduction chunks per batch
#define CHROWS_ (L_ / NCH_)        // 48

__device__ __forceinline__ void atomAddF(float* p, float v) {
    unsafeAtomicAdd(p, v);   // native global_atomic_add_f32 on gfx950
}

// ---------------------------------------------------------------------------
// Kernel M: normalize mask to int32 regardless of stored dtype.
__global__ __launch_bounds__(256) void k_mask(const void* __restrict__ mask_raw,
                                              int* __restrict__ maskN, int n) {
    const unsigned int* dw = (const unsigned int*)mask_raw;
    int tid = threadIdx.x;
    int local_int = 1, local_flt = 1;
    for (int i = tid; i < n / 4; i += blockDim.x) {
        unsigned int v = dw[i];
        if (v != 0u && v != 1u) local_int = 0;
        if (v != 0u && v != 0x3F800000u) local_flt = 0;
    }
    int all_int = __syncthreads_and(local_int);
    int all_flt = __syncthreads_and(local_flt);
    if (all_int) {
        for (int i = tid; i < n; i += blockDim.x) maskN[i] = (dw[i] != 0u) ? 1 : 0;
    } else if (all_flt) {
        const float* f = (const float*)mask_raw;
        for (int i = tid; i < n; i += blockDim.x) maskN[i] = (f[i] != 0.0f) ? 1 : 0;
    } else {
        const unsigned char* by = (const unsigned char*)mask_raw;
        for (int i = tid; i < n; i += blockDim.x) maskN[i] = by[i] ? 1 : 0;
    }
}

// ---------------------------------------------------------------------------
// Kernel P: symmetric tile-pair pass over the pair tensor.
// Block = (b, ta<=tb). Each unordered row pair {i,j} is evaluated once:
// y = LN(p_sym(i,j)) contributes to rows i (registers) and j (per-wave LDS),
// then atomically accumulated into rs_inter/rs_intra (+ scalar dens).
// Diagonal tiles use fac=0.5 (each unordered pair visited twice).
// Loads are SKIPPED when both weights are zero (mask/chain/band) - wave-uniform.
__global__ __launch_bounds__(256) void k_pair_tiles(
    const float* __restrict__ pair, const float* __restrict__ gz,
    const float* __restrict__ bz, const int* __restrict__ chain,
    const int* __restrict__ maskN,
    float* __restrict__ rs_inter, float* __restrict__ rs_intra,
    float* __restrict__ den_inter, float* __restrict__ den_intra) {
    extern __shared__ float lds[];
    float* smJI = lds;                    // [4][16][128]
    float* smJA = smJI + 4 * 16 * 128;    // [4][16][128]
    float* smDJI = smJA + 4 * 16 * 128;   // [4][16]
    float* smDJA = smDJI + 64;            // [4][16]
    int* s_mi = (int*)(smDJA + 64);       // [16]
    int* s_ci = s_mi + 16;
    int* s_mj = s_ci + 16;
    int* s_cj = s_mj + 16;

    const int b = blockIdx.x / NTP_;
    int t = blockIdx.x % NTP_;
    int ta = 0;
    while (t >= NT_ - ta) { t -= NT_ - ta; ta++; }
    const int tb = ta + t;
    const int i0 = ta * T_, j0 = tb * T_;
    const float fac = (ta == tb) ? 0.5f : 1.0f;

    const int tid = threadIdx.x;
    const int wave = tid >> 6, lane = tid & 63;
    const int ch2 = lane * 2;

    for (int idx = tid; idx < 4 * 16 * 128; idx += 256) { smJI[idx] = 0.f; smJA[idx] = 0.f; }
    if (tid < 64) { smDJI[tid] = 0.f; smDJA[tid] = 0.f; }
    if (tid < 16) {
        s_mi[tid] = maskN[b * L_ + i0 + tid];
        s_ci[tid] = chain[b * L_ + i0 + tid];
        s_mj[tid] = maskN[b * L_ + j0 + tid];
        s_cj[tid] = chain[b * L_ + j0 + tid];
    }
    __syncthreads();

    const float g0 = gz[ch2], g1 = gz[ch2 + 1];
    const float bb0 = bz[ch2], bb1 = bz[ch2 + 1];
    const float* baseb = pair + (size_t)b * L_ * L_ * DP_;

    float accI0[4] = {0, 0, 0, 0}, accI1[4] = {0, 0, 0, 0};
    float accA0[4] = {0, 0, 0, 0}, accA1[4] = {0, 0, 0, 0};
    float denI[4] = {0, 0, 0, 0}, denA[4] = {0, 0, 0, 0};

    for (int r = 0; r < 4; ++r) {
        const int il = (wave << 2) + r;
        const int gi = i0 + il;
        const int mi_ = s_mi[il];
        const int ci_ = s_ci[il];
        if (!mi_) continue;
        for (int jl = 0; jl < 16; ++jl) {
            const int gj = j0 + jl;
            if (!s_mj[jl]) continue;
            const bool same = (s_cj[jl] == ci_);
            int d = gi - gj; d = d < 0 ? -d : d;
            const float wI = (!same) ? fac : 0.f;
            const float wA = (same && d <= NB_) ? fac : 0.f;
            if (wI == 0.f && wA == 0.f) continue;
            float v0, v1;
            if (gi == gj) {
                v0 = 0.f; v1 = 0.f;     // zeroed diagonal -> LN(0) = bz
            } else {
                const float2 a = *(const float2*)(baseb + ((size_t)gi * L_ + gj) * DP_ + ch2);
                const float2 c = *(const float2*)(baseb + ((size_t)gj * L_ + gi) * DP_ + ch2);
                v0 = 0.5f * (a.x + c.x); v1 = 0.5f * (a.y + c.y);
            }
            float s = v0 + v1, q = v0 * v0 + v1 * v1;
            #pragma unroll
            for (int off = 32; off; off >>= 1) {
                s += __shfl_xor(s, off);
                q += __shfl_xor(q, off);
            }
            const float mu = s * (1.f / DP_);
            const float rstd = rsqrtf(q * (1.f / DP_) - mu * mu + LN_EPS_);
            const float y0 = (v0 - mu) * rstd * g0 + bb0;
            const float y1 = (v1 - mu) * rstd * g1 + bb1;
            accI0[r] += wI * y0; accI1[r] += wI * y1;
            accA0[r] += wA * y0; accA1[r] += wA * y1;
            denI[r] += wI; denA[r] += wA;
            float* pJI = smJI + ((wave * 16 + jl) << 7) + ch2;
            float* pJA = smJA + ((wave * 16 + jl) << 7) + ch2;
            pJI[0] += wI * y0; pJI[1] += wI * y1;
            pJA[0] += wA * y0; pJA[1] += wA * y1;
            if (lane == 0) { smDJI[wave * 16 + jl] += wI; smDJA[wave * 16 + jl] += wA; }
        }
    }
    __syncthreads();
    // i-side (registers)
    #pragma unroll
    for (int r = 0; r < 4; ++r) {
        const int gi = i0 + (wave << 2) + r;
        const size_t o = ((size_t)(b * L_ + gi) << 7) + ch2;
        atomAddF(&rs_inter[o], accI0[r]);
        atomAddF(&rs_inter[o + 1], accI1[r]);
        atomAddF(&rs_intra[o], accA0[r]);
        atomAddF(&rs_intra[o + 1], accA1[r]);
        if (lane == 0) {
            atomAddF(&den_inter[b * L_ + gi], denI[r]);
            atomAddF(&den_intra[b * L_ + gi], denA[r]);
        }
    }
    // j-side (LDS, reduced over 4 wave-copies)
    for (int idx = tid; idx < 16 * 128; idx += 256) {
        const int jl = idx >> 7, ch = idx & 127;
        const float vI = smJI[idx] + smJI[idx + 2048] + smJI[idx + 4096] + smJI[idx + 6144];
        const float vA = smJA[idx] + smJA[idx + 2048] + smJA[idx + 4096] + smJA[idx + 6144];
        const size_t o = ((size_t)(b * L_ + j0 + jl) << 7) + ch;
        atomAddF(&rs_inter[o], vI);
        atomAddF(&rs_intra[o], vA);
    }
    if (tid < 16) {
        const float dI = smDJI[tid] + smDJI[16 + tid] + smDJI[32 + tid] + smDJI[48 + tid];
        const float dA = smDJA[tid] + smDJA[16 + tid] + smDJA[32 + tid] + smDJA[48 + tid];
        atomAddF(&den_inter[b * L_ + j0 + tid], dI);
        atomAddF(&den_intra[b * L_ + j0 + tid], dA);
    }
}

// ---------------------------------------------------------------------------
// Kernel S1: s = LN(seq_repr) @ W_seq, 4 rows per block.
#define SROWS_ 4
__global__ __launch_bounds__(384) void k_seq_proj(
    const float* __restrict__ seq, const float* __restrict__ gs,
    const float* __restrict__ bs, const float* __restrict__ W,
    float* __restrict__ s_rows) {
    const int row0 = blockIdx.x * SROWS_;
    const int tid = threadIdx.x;
    const int wave = tid >> 6, lane = tid & 63;
    __shared__ float xn[SROWS_][DS_];
    __shared__ float sSum[SROWS_][6], sSq[SROWS_][6];
    const float gg = gs[tid], bbv = bs[tid];
    #pragma unroll
    for (int r = 0; r < SROWS_; r++) {
        float x = seq[(size_t)(row0 + r) * DS_ + tid];
        float s = x, q = x * x;
        #pragma unroll
        for (int off = 32; off; off >>= 1) {
            s += __shfl_xor(s, off);
            q += __shfl_xor(q, off);
        }
        if (lane == 0) { sSum[r][wave] = s; sSq[r][wave] = q; }
        xn[r][tid] = x;
    }
    __syncthreads();
    float mu[SROWS_], rstd[SROWS_];
    #pragma unroll
    for (int r = 0; r < SROWS_; r++) {
        float ts = 0.f, tq = 0.f;
        #pragma unroll
        for (int w = 0; w < 6; w++) { ts += sSum[r][w]; tq += sSq[r][w]; }
        mu[r] = ts * (1.0f / DS_);
        float var = tq * (1.0f / DS_) - mu[r] * mu[r];
        rstd[r] = rsqrtf(var + LN_EPS_);
    }
    #pragma unroll
    for (int r = 0; r < SROWS_; r++)
        xn[r][tid] = (xn[r][tid] - mu[r]) * rstd[r] * gg + bbv;
    __syncthreads();
    float acc[SROWS_] = {0.f, 0.f, 0.f, 0.f};
    for (int k = 0; k < DS_; k++) {
        float w = W[(size_t)k * DS_ + tid];
        #pragma unroll
        for (int r = 0; r < SROWS_; r++) acc[r] += xn[r][k] * w;
    }
    #pragma unroll
    for (int r = 0; r < SROWS_; r++)
        s_rows[(size_t)(row0 + r) * DS_ + tid] = acc[r];
}

// ---------------------------------------------------------------------------
// Kernel S2a: partial masked sum/max over 48-row chunks (32 blocks).
__global__ __launch_bounds__(384) void k_seq_partial(
    const float* __restrict__ s_rows, const int* __restrict__ maskN,
    float* __restrict__ psum, float* __restrict__ pmax, int* __restrict__ pcnt) {
    const int b = blockIdx.x / NCH_, c = blockIdx.x % NCH_;
    const int ch = threadIdx.x;
    float sum = 0.f, mx = -INFINITY;
    int cnt = 0;
    const int l0 = c * CHROWS_;
    for (int l = l0; l < l0 + CHROWS_; ++l) {
        if (maskN[b * L_ + l]) {
            float v = s_rows[(size_t)(b * L_ + l) * DS_ + ch];
            sum += v; mx = fmaxf(mx, v); cnt++;
        }
    }
    psum[(size_t)blockIdx.x * DS_ + ch] = sum;
    pmax[(size_t)blockIdx.x * DS_ + ch] = mx;
    if (ch == 0) pcnt[blockIdx.x] = cnt;
}

// ---------------------------------------------------------------------------
// Kernel P2: pair partials over 48-row chunks (32 blocks). Computes row
// projections (W_pair staged in LDS), chunk peak, chunk sums and dens.
__global__ __launch_bounds__(128) void k_pair_partial(
    const float* __restrict__ rs_inter, const float* __restrict__ rs_intra,
    const float* __restrict__ den_inter, const float* __restrict__ den_intra,
    const float* __restrict__ Wp,
    float* __restrict__ pI, float* __restrict__ pA, float* __restrict__ pPk,
    float* __restrict__ pdI, float* __restrict__ pdA) {
    extern __shared__ float lds2[];
    float* sWp = lds2;             // [128][128]
    float* sRS = sWp + 128 * 128;  // [128]
    const int b = blockIdx.x / NCH_, c = blockIdx.x % NCH_;
    const int ch = threadIdx.x;
    for (int idx = ch; idx < 128 * 128; idx += 128) sWp[idx] = Wp[idx];
    float totI = 0.f, totA = 0.f, dI = 0.f, dA = 0.f, peak = -INFINITY;
    const int r0 = b * L_ + c * CHROWS_;
    for (int r = 0; r < CHROWS_; ++r) {
        __syncthreads();
        const float vI = rs_inter[(size_t)(r0 + r) * DP_ + ch];
        sRS[ch] = vI;
        totI += vI;
        totA += rs_intra[(size_t)(r0 + r) * DP_ + ch];
        const float den = den_inter[r0 + r];
        dI += den; dA += den_intra[r0 + r];
        __syncthreads();
        float acc = 0.f;
        for (int k = 0; k < 128; ++k) acc += sRS[k] * sWp[(k << 7) + ch];
        peak = fmaxf(peak, acc / fmaxf(den, 1e-6f));
    }
    pI[(size_t)blockIdx.x * DP_ + ch] = totI;
    pA[(size_t)blockIdx.x * DP_ + ch] = totA;
    pPk[(size_t)blockIdx.x * DP_ + ch] = peak;
    if (ch == 0) { pdI[blockIdx.x] = dI; pdA[blockIdx.x] = dA; }
}

// ---------------------------------------------------------------------------
// Kernel F: fused finalize per batch: combine partials, both gates, MLP head.
__global__ __launch_bounds__(384) void k_finalize(
    const float* __restrict__ psum, const float* __restrict__ pmax,
    const int* __restrict__ pcnt,
    const float* __restrict__ pI, const float* __restrict__ pA,
    const float* __restrict__ pPk,
    const float* __restrict__ pdI, const float* __restrict__ pdA,
    const float* __restrict__ Wgs, const float* __restrict__ bgs,
    const float* __restrict__ Wp, const float* __restrict__ Wgz,
    const float* __restrict__ bgz,
    const float* __restrict__ W1, const float* __restrict__ b1,
    const float* __restrict__ W2, const float* __restrict__ b2,
    float* __restrict__ out) {
    const int b = blockIdx.x;
    const int tid = threadIdx.x;
    __shared__ float sMean[DS_], sMax[DS_], fI[DP_], fA[DP_], sPk[DP_], sIM[DP_];
    __shared__ float feat[FEAT_];
    __shared__ float sdI, sdA;
    {   // seq combine
        float s = 0.f, m = -INFINITY;
        int cnt = 0;
        for (int c = 0; c < NCH_; ++c) {
            s += psum[(size_t)(b * NCH_ + c) * DS_ + tid];
            m = fmaxf(m, pmax[(size_t)(b * NCH_ + c) * DS_ + tid]);
            cnt += pcnt[b * NCH_ + c];
        }
        sMean[tid] = s / fmaxf((float)cnt, 1e-6f);
        sMax[tid] = (cnt > 0) ? m : 0.f;
    }
    if (tid < DP_) {  // pair combine
        float tI = 0.f, tA = 0.f, pk = -INFINITY, ddI = 0.f, ddA = 0.f;
        for (int c = 0; c < NCH_; ++c) {
            tI += pI[(size_t)(b * NCH_ + c) * DP_ + tid];
            tA += pA[(size_t)(b * NCH_ + c) * DP_ + tid];
            pk = fmaxf(pk, pPk[(size_t)(b * NCH_ + c) * DP_ + tid]);
            ddI += pdI[b * NCH_ + c]; ddA += pdA[b * NCH_ + c];
        }
        fI[tid] = tI; fA[tid] = tA; sPk[tid] = pk;
        if (tid == 0) { sdI = ddI; sdA = ddA; }
    }
    __syncthreads();
    {   // seq gate + s_feat
        float acc = bgs[tid];
        for (int k = 0; k < DS_; ++k)
            acc += sMax[k] * Wgs[(size_t)k * DS_ + tid]
                 + sMean[k] * Wgs[(size_t)(k + DS_) * DS_ + tid];
        const float gate = 1.f / (1.f + expf(-acc));
        feat[tid] = sMean[tid] + gate * (sMax[tid] - sMean[tid]);
    }
    if (tid < DP_) {  // inter_mean / intra_compact projections
        float aI = 0.f, aA = 0.f;
        for (int k = 0; k < DP_; ++k) {
            aI += fI[k] * Wp[(k << 7) + tid];
            aA += fA[k] * Wp[(k << 7) + tid];
        }
        sIM[tid] = aI / fmaxf(sdI, 1e-6f);
        feat[DS_ + DP_ + tid] = aA / fmaxf(sdA, 1e-6f);
    }
    __syncthreads();
    if (tid < DP_) {  // pair gate
        float acc = bgz[tid];
        for (int k = 0; k < DP_; ++k)
            acc += sPk[k] * Wgz[(k << 7) + tid] + sIM[k] * Wgz[((k + DP_) << 7) + tid];
        const float gate = 1.f / (1.f + expf(-acc));
        feat[DS_ + tid] = sIM[tid] + gate * (sPk[tid] - sIM[tid]);
    }
    __syncthreads();
    if (tid < 64) {   // MLP head
        float acc = b1[tid];
        for (int k = 0; k < FEAT_; ++k) acc += feat[k] * W1[(k << 6) + tid];
        float p = fmaxf(acc, 0.f) * W2[tid];
        #pragma unroll
        for (int off = 32; off; off >>= 1) p += __shfl_xor(p, off);
        if (tid == 0) out[b] = 1.f / (1.f + expf(-(p + b2[0])));
    }
}

// ---------------------------------------------------------------------------
extern "C" void kernel_launch(void* const* d_in, const int* in_sizes, int n_in,
                              void* d_out, int out_size, void* d_ws, size_t ws_size,
                              hipStream_t stream) {
    const float* seq    = (const float*)d_in[0];
    const float* pair   = (const float*)d_in[1];
    const float* ln_s_g = (const float*)d_in[2];
    const float* ln_s_b = (const float*)d_in[3];
    const float* ln_z_g = (const float*)d_in[4];
    const float* ln_z_b = (const float*)d_in[5];
    const float* W_seq  = (const float*)d_in[6];
    const float* W_pair = (const float*)d_in[7];
    const float* W_gs   = (const float*)d_in[8];
    const float* b_gs   = (const float*)d_in[9];
    const float* W_gz   = (const float*)d_in[10];
    const float* b_gz   = (const float*)d_in[11];
    const float* W1     = (const float*)d_in[12];
    const float* b1     = (const float*)d_in[13];
    const float* W2     = (const float*)d_in[14];
    const float* b2     = (const float*)d_in[15];
    const int*   chain  = (const int*)d_in[16];
    const void*  mask   = d_in[17];
    float* out = (float*)d_out;

    // workspace layout — atomic-accumulated region first (zeroed every launch)
    char* ws = (char*)d_ws;
    float* rs_inter  = (float*)ws;  ws += (size_t)B_ * L_ * DP_ * 4;
    float* rs_intra  = (float*)ws;  ws += (size_t)B_ * L_ * DP_ * 4;
    float* den_inter = (float*)ws;  ws += (size_t)B_ * L_ * 4;
    float* den_intra = (float*)ws;  ws += (size_t)B_ * L_ * 4;
    const size_t zero_bytes = ((size_t)2 * B_ * L_ * DP_ + 2 * B_ * L_) * 4;
    int*   maskN = (int*)ws;        ws += (size_t)B_ * L_ * 4;
    float* s_rows = (float*)ws;     ws += (size_t)B_ * L_ * DS_ * 4;
    float* psum = (float*)ws;       ws += (size_t)B_ * NCH_ * DS_ * 4;
    float* pmax = (float*)ws;       ws += (size_t)B_ * NCH_ * DS_ * 4;
    int*   pcnt = (int*)ws;         ws += (size_t)B_ * NCH_ * 4;
    float* pI   = (float*)ws;       ws += (size_t)B_ * NCH_ * DP_ * 4;
    float* pA   = (float*)ws;       ws += (size_t)B_ * NCH_ * DP_ * 4;
    float* pPk  = (float*)ws;       ws += (size_t)B_ * NCH_ * DP_ * 4;
    float* pdI  = (float*)ws;       ws += (size_t)B_ * NCH_ * 4;
    float* pdA  = (float*)ws;       ws += (size_t)B_ * NCH_ * 4;

    const size_t ldsTiles = (size_t)(2 * 4 * 16 * 128 + 128 + 64) * 4;  // ~66.3 KB
    const size_t ldsPP    = (size_t)(128 * 128 + 128) * 4;              // ~66.0 KB

    hipMemsetAsync(rs_inter, 0, zero_bytes, stream);
    k_mask<<<1, 256, 0, stream>>>(mask, maskN, B_ * L_);
    k_pair_tiles<<<B_ * NTP_, 256, ldsTiles, stream>>>(
        pair, ln_z_g, ln_z_b, chain, maskN, rs_inter, rs_intra, den_inter, den_intra);
    k_seq_proj<<<(B_ * L_) / SROWS_, 384, 0, stream>>>(seq, ln_s_g, ln_s_b, W_seq, s_rows);
    k_seq_partial<<<B_ * NCH_, 384, 0, stream>>>(s_rows, maskN, psum, pmax, pcnt);
    k_pair_partial<<<B_ * NCH_, 128, ldsPP, stream>>>(
        rs_inter, rs_intra, den_inter, den_intra, W_pair, pI, pA, pPk, pdI, pdA);
    k_finalize<<<B_, 384, 0, stream>>>(psum, pmax, pcnt, pI, pA, pPk, pdI, pdA,
                                       W_gs, b_gs, W_pair, W_gz, b_gz,
                                       W1, b1, W2, b2, out);
}

// Round 5
// 655.258 us; speedup vs baseline: 1.0454x; 1.0454x over previous
//
#include <hip/hip_runtime.h>
#include <math.h>

// Problem constants
#define B_  4
#define L_  384
#define DS_ 384
#define DP_ 128
#define NB_ 4
#define FEAT_ (DS_ + 2*DP_)   // 640
#define LN_EPS_ 1e-5f
#define T_ 16
#define NT_ (L_ / T_)              // 24 tiles
#define NTP_ (NT_ * (NT_ + 1) / 2) // 300 tile-pairs (ta<=tb)
#define SROWS_ 4

// ---------------------------------------------------------------------------
// Inline mask-dtype detection (whole block participates; 384 dwords is safe
// to read under int32 / float32 / byte-bool layouts of the [B,L] mask).
__device__ __forceinline__ int detect_mode_block(const void* __restrict__ raw) {
    const unsigned int* dw = (const unsigned int*)raw;
    int li = 1, lf = 1;
    for (int i = threadIdx.x; i < (B_ * L_) / 4; i += blockDim.x) {
        unsigned int v = dw[i];
        if (v != 0u && v != 1u) li = 0;
        if (v != 0u && v != 0x3F800000u) lf = 0;
    }
    int ai = __syncthreads_and(li);
    int af = __syncthreads_and(lf);
    return ai ? 0 : (af ? 1 : 2);   // 0=int32, 1=float32, 2=byte
}
__device__ __forceinline__ int mask_at(const void* __restrict__ raw, int mode, int idx) {
    if (mode == 0) return ((const unsigned int*)raw)[idx] != 0u;
    if (mode == 1) return ((const float*)raw)[idx] != 0.0f;
    return ((const unsigned char*)raw)[idx] != 0;
}

// index helpers for the partial buffers P[b][tile][slot][row16][ch128]
__device__ __forceinline__ size_t poff(int b, int tile, int slot, int row) {
    return ((((size_t)b * NT_ + tile) * NT_ + slot) * T_ + row) * DP_;
}
__device__ __forceinline__ size_t pdoff(int b, int tile, int slot, int row) {
    return (((size_t)b * NT_ + tile) * NT_ + slot) * T_ + row;
}

// ---------------------------------------------------------------------------
// Kernel P: symmetric tile-pair pass. Block = (b, ta<=tb). Each unordered row
// pair {i,j} evaluated once: y = LN(p_sym(i,j)) goes to row i (registers) and
// row j (single shared accumulator via LDS atomicAdd). NO global atomics:
// block (ta,tb) writes i-side partial to P[b][ta][slot=tb] and j-side partial
// to P[b][tb][slot=ta]; diagonal block writes reg+LDS combined to its slot.
// Every (tile,slot) written exactly once -> no zero-init of workspace needed.
__global__ __launch_bounds__(256) void k_pair_tiles(
    const float* __restrict__ pair, const float* __restrict__ gz,
    const float* __restrict__ bz, const int* __restrict__ chain,
    const void* __restrict__ mask_raw,
    float* __restrict__ PI, float* __restrict__ PA,
    float* __restrict__ PDI, float* __restrict__ PDA) {
    __shared__ float smJI[T_][DP_], smJA[T_][DP_];   // 16 KB total
    __shared__ float smDJI[T_], smDJA[T_];
    __shared__ int s_m[2 * T_], s_c[2 * T_];

    const int mode = detect_mode_block(mask_raw);    // block-wide, has syncs

    const int b = blockIdx.x / NTP_;
    int t = blockIdx.x % NTP_;
    int ta = 0;
    while (t >= NT_ - ta) { t -= NT_ - ta; ta++; }
    const int tb = ta + t;
    const int i0 = ta * T_, j0 = tb * T_;
    const float fac = (ta == tb) ? 0.5f : 1.0f;

    const int tid = threadIdx.x;
    const int wave = tid >> 6, lane = tid & 63;
    const int ch2 = lane * 2;

    for (int idx = tid; idx < T_ * DP_; idx += 256) {
        (&smJI[0][0])[idx] = 0.f;
        (&smJA[0][0])[idx] = 0.f;
    }
    if (tid < T_) { smDJI[tid] = 0.f; smDJA[tid] = 0.f; }
    if (tid < 2 * T_) {
        const int loc = (tid < T_) ? (i0 + tid) : (j0 + tid - T_);
        s_m[tid] = mask_at(mask_raw, mode, b * L_ + loc);
        s_c[tid] = chain[b * L_ + loc];
    }
    __syncthreads();

    const float g0 = gz[ch2], g1 = gz[ch2 + 1];
    const float bb0 = bz[ch2], bb1 = bz[ch2 + 1];
    const float* baseb = pair + (size_t)b * L_ * L_ * DP_;

    float accI0[4] = {0, 0, 0, 0}, accI1[4] = {0, 0, 0, 0};
    float accA0[4] = {0, 0, 0, 0}, accA1[4] = {0, 0, 0, 0};
    float denI[4] = {0, 0, 0, 0}, denA[4] = {0, 0, 0, 0};

    for (int r = 0; r < 4; ++r) {
        const int il = (wave << 2) + r;
        const int gi = i0 + il;
        if (!s_m[il]) continue;
        const int ci = s_c[il];
        for (int jl = 0; jl < T_; ++jl) {
            if (!s_m[T_ + jl]) continue;              // wave-uniform skip
            const int gj = j0 + jl;
            const bool same = (s_c[T_ + jl] == ci);
            int d = gi - gj; d = d < 0 ? -d : d;
            const float wI = (!same) ? fac : 0.f;
            const float wA = (same && d <= NB_) ? fac : 0.f;
            if (wI == 0.f && wA == 0.f) continue;     // wave-uniform skip
            float v0, v1;
            if (gi == gj) {
                v0 = 0.f; v1 = 0.f;                   // zeroed diag -> LN(0)=bz
            } else {
                const float2 a = *(const float2*)(baseb + ((size_t)gi * L_ + gj) * DP_ + ch2);
                const float2 c = *(const float2*)(baseb + ((size_t)gj * L_ + gi) * DP_ + ch2);
                v0 = 0.5f * (a.x + c.x); v1 = 0.5f * (a.y + c.y);
            }
            float s = v0 + v1, q = v0 * v0 + v1 * v1;
            #pragma unroll
            for (int off = 32; off; off >>= 1) {
                s += __shfl_xor(s, off);
                q += __shfl_xor(q, off);
            }
            const float mu = s * (1.f / DP_);
            const float rstd = rsqrtf(q * (1.f / DP_) - mu * mu + LN_EPS_);
            const float y0 = (v0 - mu) * rstd * g0 + bb0;
            const float y1 = (v1 - mu) * rstd * g1 + bb1;
            accI0[r] += wI * y0; accI1[r] += wI * y1;
            accA0[r] += wA * y0; accA1[r] += wA * y1;
            denI[r] += wI; denA[r] += wA;
            if (wI != 0.f) {
                atomicAdd(&smJI[jl][ch2], wI * y0);
                atomicAdd(&smJI[jl][ch2 + 1], wI * y1);
                if (lane == 0) atomicAdd(&smDJI[jl], wI);
            }
            if (wA != 0.f) {
                atomicAdd(&smJA[jl][ch2], wA * y0);
                atomicAdd(&smJA[jl][ch2 + 1], wA * y1);
                if (lane == 0) atomicAdd(&smDJA[jl], wA);
            }
        }
    }
    __syncthreads();

    if (ta != tb) {
        // i-side partial (registers) -> tile ta, slot tb
        #pragma unroll
        for (int r = 0; r < 4; ++r) {
            const int il = (wave << 2) + r;
            const size_t o = poff(b, ta, tb, il) + ch2;
            PI[o] = accI0[r]; PI[o + 1] = accI1[r];
            PA[o] = accA0[r]; PA[o + 1] = accA1[r];
            if (lane == 0) {
                PDI[pdoff(b, ta, tb, il)] = denI[r];
                PDA[pdoff(b, ta, tb, il)] = denA[r];
            }
        }
        // j-side partial (LDS) -> tile tb, slot ta
        for (int idx = tid; idx < T_ * DP_; idx += 256) {
            const int jl = idx >> 7, ch = idx & 127;
            const size_t o = poff(b, tb, ta, jl) + ch;
            PI[o] = smJI[jl][ch];
            PA[o] = smJA[jl][ch];
        }
        if (tid < T_) {
            PDI[pdoff(b, tb, ta, tid)] = smDJI[tid];
            PDA[pdoff(b, tb, ta, tid)] = smDJA[tid];
        }
    } else {
        // diagonal: combined reg+LDS -> tile ta, slot ta (written once)
        #pragma unroll
        for (int r = 0; r < 4; ++r) {
            const int il = (wave << 2) + r;
            const size_t o = poff(b, ta, ta, il) + ch2;
            PI[o] = accI0[r] + smJI[il][ch2];
            PI[o + 1] = accI1[r] + smJI[il][ch2 + 1];
            PA[o] = accA0[r] + smJA[il][ch2];
            PA[o + 1] = accA1[r] + smJA[il][ch2 + 1];
            if (lane == 0) {
                PDI[pdoff(b, ta, ta, il)] = denI[r] + smDJI[il];
                PDA[pdoff(b, ta, ta, il)] = denA[r] + smDJA[il];
            }
        }
    }
}

// ---------------------------------------------------------------------------
// Kernel S1: s = LN(seq_repr) @ W_seq, 4 rows per block. (unchanged, verified)
__global__ __launch_bounds__(384) void k_seq_proj(
    const float* __restrict__ seq, const float* __restrict__ gs,
    const float* __restrict__ bs, const float* __restrict__ W,
    float* __restrict__ s_rows) {
    const int row0 = blockIdx.x * SROWS_;
    const int tid = threadIdx.x;
    const int wave = tid >> 6, lane = tid & 63;
    __shared__ float xn[SROWS_][DS_];
    __shared__ float sSum[SROWS_][6], sSq[SROWS_][6];
    const float gg = gs[tid], bbv = bs[tid];
    #pragma unroll
    for (int r = 0; r < SROWS_; r++) {
        float x = seq[(size_t)(row0 + r) * DS_ + tid];
        float s = x, q = x * x;
        #pragma unroll
        for (int off = 32; off; off >>= 1) {
            s += __shfl_xor(s, off);
            q += __shfl_xor(q, off);
        }
        if (lane == 0) { sSum[r][wave] = s; sSq[r][wave] = q; }
        xn[r][tid] = x;
    }
    __syncthreads();
    float mu[SROWS_], rstd[SROWS_];
    #pragma unroll
    for (int r = 0; r < SROWS_; r++) {
        float ts = 0.f, tq = 0.f;
        #pragma unroll
        for (int w = 0; w < 6; w++) { ts += sSum[r][w]; tq += sSq[r][w]; }
        mu[r] = ts * (1.0f / DS_);
        float var = tq * (1.0f / DS_) - mu[r] * mu[r];
        rstd[r] = rsqrtf(var + LN_EPS_);
    }
    #pragma unroll
    for (int r = 0; r < SROWS_; r++)
        xn[r][tid] = (xn[r][tid] - mu[r]) * rstd[r] * gg + bbv;
    __syncthreads();
    float acc[SROWS_] = {0.f, 0.f, 0.f, 0.f};
    for (int k = 0; k < DS_; k++) {
        float w = W[(size_t)k * DS_ + tid];
        #pragma unroll
        for (int r = 0; r < SROWS_; r++) acc[r] += xn[r][k] * w;
    }
    #pragma unroll
    for (int r = 0; r < SROWS_; r++)
        s_rows[(size_t)(row0 + r) * DS_ + tid] = acc[r];
}

// ---------------------------------------------------------------------------
// Kernel M (mid): role-split by blockIdx.
//  blocks [0, 96):    pair role (b,tile): reduce 24 slots -> row sums, project
//                     rows through W_pair (LDS) for peak; emit chunk partials.
//  blocks [96, 192):  seq role (b,tile): masked sum/max/count over 16 rows.
__global__ __launch_bounds__(384) void k_mid(
    const float* __restrict__ s_rows, const void* __restrict__ mask_raw,
    const float* __restrict__ Wp,
    const float* __restrict__ PI, const float* __restrict__ PA,
    const float* __restrict__ PDI, const float* __restrict__ PDA,
    float* __restrict__ psum, float* __restrict__ pmax, int* __restrict__ pcnt,
    float* __restrict__ pI, float* __restrict__ pA, float* __restrict__ pPk,
    float* __restrict__ pdI, float* __restrict__ pdA) {
    __shared__ float sWp[DP_ * DP_];   // 64 KB
    __shared__ float sRS[DP_];
    const int tid = threadIdx.x;

    if (blockIdx.x < B_ * NT_) {
        const int b = blockIdx.x / NT_, tile = blockIdx.x % NT_;
        for (int i = tid; i < DP_ * DP_; i += 384) sWp[i] = Wp[i];
        __syncthreads();
        float totI = 0.f, totA = 0.f, dI = 0.f, dA = 0.f, peak = -INFINITY;
        for (int r = 0; r < T_; ++r) {
            float dr = 0.f;
            if (tid < DP_) {
                float rsI = 0.f, rsA = 0.f, da = 0.f;
                const size_t o0 = poff(b, tile, 0, r) + tid;
                const size_t d0 = pdoff(b, tile, 0, r);
                #pragma unroll 4
                for (int s = 0; s < NT_; ++s) {
                    rsI += PI[o0 + (size_t)s * T_ * DP_];
                    rsA += PA[o0 + (size_t)s * T_ * DP_];
                    dr += PDI[d0 + (size_t)s * T_];
                    da += PDA[d0 + (size_t)s * T_];
                }
                sRS[tid] = rsI;
                totI += rsI; totA += rsA; dI += dr; dA += da;
            }
            __syncthreads();
            if (tid < DP_) {
                float acc = 0.f;
                #pragma unroll 8
                for (int k = 0; k < DP_; ++k) acc += sRS[k] * sWp[(k << 7) + tid];
                peak = fmaxf(peak, acc / fmaxf(dr, 1e-6f));
            }
            __syncthreads();
        }
        if (tid < DP_) {
            pI[(size_t)(b * NT_ + tile) * DP_ + tid] = totI;
            pA[(size_t)(b * NT_ + tile) * DP_ + tid] = totA;
            pPk[(size_t)(b * NT_ + tile) * DP_ + tid] = peak;
            if (tid == 0) { pdI[b * NT_ + tile] = dI; pdA[b * NT_ + tile] = dA; }
        }
    } else {
        const int bi = blockIdx.x - B_ * NT_;
        const int b = bi / NT_, tile = bi % NT_;
        const int mode = detect_mode_block(mask_raw);
        float sum = 0.f, mx = -INFINITY;
        int cnt = 0;
        const int l0 = tile * T_;
        for (int l = l0; l < l0 + T_; ++l) {
            if (mask_at(mask_raw, mode, b * L_ + l)) {
                float v = s_rows[(size_t)(b * L_ + l) * DS_ + tid];
                sum += v; mx = fmaxf(mx, v); cnt++;
            }
        }
        psum[(size_t)(b * NT_ + tile) * DS_ + tid] = sum;
        pmax[(size_t)(b * NT_ + tile) * DS_ + tid] = mx;
        if (tid == 0) pcnt[b * NT_ + tile] = cnt;
    }
}

// ---------------------------------------------------------------------------
// Kernel F: fused finalize per batch: combine 24 chunks, both gates, MLP head.
__global__ __launch_bounds__(384) void k_finalize(
    const float* __restrict__ psum, const float* __restrict__ pmax,
    const int* __restrict__ pcnt,
    const float* __restrict__ pI, const float* __restrict__ pA,
    const float* __restrict__ pPk,
    const float* __restrict__ pdI, const float* __restrict__ pdA,
    const float* __restrict__ Wgs, const float* __restrict__ bgs,
    const float* __restrict__ Wp, const float* __restrict__ Wgz,
    const float* __restrict__ bgz,
    const float* __restrict__ W1, const float* __restrict__ b1,
    const float* __restrict__ W2, const float* __restrict__ b2,
    float* __restrict__ out) {
    const int b = blockIdx.x;
    const int tid = threadIdx.x;
    __shared__ float sMean[DS_], sMax[DS_], fI[DP_], fA[DP_], sPk[DP_], sIM[DP_];
    __shared__ float feat[FEAT_];
    __shared__ float sdI, sdA;
    {   // seq combine
        float s = 0.f, m = -INFINITY;
        int cnt = 0;
        for (int c = 0; c < NT_; ++c) {
            s += psum[(size_t)(b * NT_ + c) * DS_ + tid];
            m = fmaxf(m, pmax[(size_t)(b * NT_ + c) * DS_ + tid]);
            cnt += pcnt[b * NT_ + c];
        }
        sMean[tid] = s / fmaxf((float)cnt, 1e-6f);
        sMax[tid] = (cnt > 0) ? m : 0.f;
    }
    if (tid < DP_) {  // pair combine
        float tI = 0.f, tA = 0.f, pk = -INFINITY, ddI = 0.f, ddA = 0.f;
        for (int c = 0; c < NT_; ++c) {
            tI += pI[(size_t)(b * NT_ + c) * DP_ + tid];
            tA += pA[(size_t)(b * NT_ + c) * DP_ + tid];
            pk = fmaxf(pk, pPk[(size_t)(b * NT_ + c) * DP_ + tid]);
            ddI += pdI[b * NT_ + c]; ddA += pdA[b * NT_ + c];
        }
        fI[tid] = tI; fA[tid] = tA; sPk[tid] = pk;
        if (tid == 0) { sdI = ddI; sdA = ddA; }
    }
    __syncthreads();
    {   // seq gate + s_feat
        float acc = bgs[tid];
        #pragma unroll 4
        for (int k = 0; k < DS_; ++k)
            acc += sMax[k] * Wgs[(size_t)k * DS_ + tid]
                 + sMean[k] * Wgs[(size_t)(k + DS_) * DS_ + tid];
        const float gate = 1.f / (1.f + expf(-acc));
        feat[tid] = sMean[tid] + gate * (sMax[tid] - sMean[tid]);
    }
    if (tid < DP_) {  // inter_mean / intra_compact projections
        float aI = 0.f, aA = 0.f;
        #pragma unroll 4
        for (int k = 0; k < DP_; ++k) {
            aI += fI[k] * Wp[(k << 7) + tid];
            aA += fA[k] * Wp[(k << 7) + tid];
        }
        sIM[tid] = aI / fmaxf(sdI, 1e-6f);
        feat[DS_ + DP_ + tid] = aA / fmaxf(sdA, 1e-6f);
    }
    __syncthreads();
    if (tid < DP_) {  // pair gate
        float acc = bgz[tid];
        #pragma unroll 4
        for (int k = 0; k < DP_; ++k)
            acc += sPk[k] * Wgz[(k << 7) + tid] + sIM[k] * Wgz[((k + DP_) << 7) + tid];
        const float gate = 1.f / (1.f + expf(-acc));
        feat[DS_ + tid] = sIM[tid] + gate * (sPk[tid] - sIM[tid]);
    }
    __syncthreads();
    if (tid < 64) {   // MLP head
        float acc = b1[tid];
        #pragma unroll 4
        for (int k = 0; k < FEAT_; ++k) acc += feat[k] * W1[(k << 6) + tid];
        float p = fmaxf(acc, 0.f) * W2[tid];
        #pragma unroll
        for (int off = 32; off; off >>= 1) p += __shfl_xor(p, off);
        if (tid == 0) out[b] = 1.f / (1.f + expf(-(p + b2[0])));
    }
}

// ---------------------------------------------------------------------------
extern "C" void kernel_launch(void* const* d_in, const int* in_sizes, int n_in,
                              void* d_out, int out_size, void* d_ws, size_t ws_size,
                              hipStream_t stream) {
    const float* seq    = (const float*)d_in[0];
    const float* pair   = (const float*)d_in[1];
    const float* ln_s_g = (const float*)d_in[2];
    const float* ln_s_b = (const float*)d_in[3];
    const float* ln_z_g = (const float*)d_in[4];
    const float* ln_z_b = (const float*)d_in[5];
    const float* W_seq  = (const float*)d_in[6];
    const float* W_pair = (const float*)d_in[7];
    const float* W_gs   = (const float*)d_in[8];
    const float* b_gs   = (const float*)d_in[9];
    const float* W_gz   = (const float*)d_in[10];
    const float* b_gz   = (const float*)d_in[11];
    const float* W1     = (const float*)d_in[12];
    const float* b1     = (const float*)d_in[13];
    const float* W2     = (const float*)d_in[14];
    const float* b2     = (const float*)d_in[15];
    const int*   chain  = (const int*)d_in[16];
    const void*  mask   = d_in[17];
    float* out = (float*)d_out;

    // workspace layout (no zero-init required: every cell written each launch)
    char* ws = (char*)d_ws;
    const size_t nP  = (size_t)B_ * NT_ * NT_ * T_ * DP_;   // 18.9 MB each
    const size_t nPD = (size_t)B_ * NT_ * NT_ * T_;
    float* PI  = (float*)ws;  ws += nP * 4;
    float* PA  = (float*)ws;  ws += nP * 4;
    float* PDI = (float*)ws;  ws += nPD * 4;
    float* PDA = (float*)ws;  ws += nPD * 4;
    float* s_rows = (float*)ws; ws += (size_t)B_ * L_ * DS_ * 4;
    float* psum = (float*)ws;   ws += (size_t)B_ * NT_ * DS_ * 4;
    float* pmax = (float*)ws;   ws += (size_t)B_ * NT_ * DS_ * 4;
    int*   pcnt = (int*)ws;     ws += (size_t)B_ * NT_ * 4;
    float* pI   = (float*)ws;   ws += (size_t)B_ * NT_ * DP_ * 4;
    float* pA   = (float*)ws;   ws += (size_t)B_ * NT_ * DP_ * 4;
    float* pPk  = (float*)ws;   ws += (size_t)B_ * NT_ * DP_ * 4;
    float* pdI  = (float*)ws;   ws += (size_t)B_ * NT_ * 4;
    float* pdA  = (float*)ws;   ws += (size_t)B_ * NT_ * 4;

    k_seq_proj<<<(B_ * L_) / SROWS_, 384, 0, stream>>>(seq, ln_s_g, ln_s_b, W_seq, s_rows);
    k_pair_tiles<<<B_ * NTP_, 256, 0, stream>>>(pair, ln_z_g, ln_z_b, chain, mask,
                                                PI, PA, PDI, PDA);
    k_mid<<<2 * B_ * NT_, 384, 0, stream>>>(s_rows, mask, W_pair, PI, PA, PDI, PDA,
                                            psum, pmax, pcnt, pI, pA, pPk, pdI, pdA);
    k_finalize<<<B_, 384, 0, stream>>>(psum, pmax, pcnt, pI, pA, pPk, pdI, pdA,
                                       W_gs, b_gs, W_pair, W_gz, b_gz,
                                       W1, b1, W2, b2, out);
}

// Round 6
// 647.762 us; speedup vs baseline: 1.0575x; 1.0116x over previous
//
#include <hip/hip_runtime.h>
#include <math.h>

// Problem constants
#define B_  4
#define L_  384
#define DS_ 384
#define DP_ 128
#define NB_ 4
#define FEAT_ (DS_ + 2*DP_)   // 640
#define LN_EPS_ 1e-5f
#define T_ 16
#define NT_ (L_ / T_)              // 24 tiles
#define NTP_ (NT_ * (NT_ + 1) / 2) // 300 tile-pairs (ta<=tb)
#define SQROWS_ 8                  // seq rows per block (role-split kernel)

// ---------------------------------------------------------------------------
// Inline mask-dtype detection (whole block participates).
__device__ __forceinline__ int detect_mode_block(const void* __restrict__ raw) {
    const unsigned int* dw = (const unsigned int*)raw;
    int li = 1, lf = 1;
    for (int i = threadIdx.x; i < (B_ * L_) / 4; i += blockDim.x) {
        unsigned int v = dw[i];
        if (v != 0u && v != 1u) li = 0;
        if (v != 0u && v != 0x3F800000u) lf = 0;
    }
    int ai = __syncthreads_and(li);
    int af = __syncthreads_and(lf);
    return ai ? 0 : (af ? 1 : 2);   // 0=int32, 1=float32, 2=byte
}
__device__ __forceinline__ int mask_at(const void* __restrict__ raw, int mode, int idx) {
    if (mode == 0) return ((const unsigned int*)raw)[idx] != 0u;
    if (mode == 1) return ((const float*)raw)[idx] != 0.0f;
    return ((const unsigned char*)raw)[idx] != 0;
}

// index helpers for the partial buffers P[b][tile][slot][row16][ch128]
__device__ __forceinline__ size_t poff(int b, int tile, int slot, int row) {
    return ((((size_t)b * NT_ + tile) * NT_ + slot) * T_ + row) * DP_;
}
__device__ __forceinline__ size_t pdoff(int b, int tile, int slot, int row) {
    return (((size_t)b * NT_ + tile) * NT_ + slot) * T_ + row;
}

// 6-level wave64 butterfly reduce of two values
#define WREDUCE2(S, Q) do { \
    (S) += __shfl_xor((S), 32); (Q) += __shfl_xor((Q), 32); \
    (S) += __shfl_xor((S), 16); (Q) += __shfl_xor((Q), 16); \
    (S) += __shfl_xor((S), 8);  (Q) += __shfl_xor((Q), 8);  \
    (S) += __shfl_xor((S), 4);  (Q) += __shfl_xor((Q), 4);  \
    (S) += __shfl_xor((S), 2);  (Q) += __shfl_xor((Q), 2);  \
    (S) += __shfl_xor((S), 1);  (Q) += __shfl_xor((Q), 1);  \
} while (0)

// LN + accumulate one eligible pair (JL wave-uniform)
#define LNACC(JL, AA, CC) do { \
    const int gj_ = j0 + (JL); \
    const bool same_ = (s_c[T_ + (JL)] == ci); \
    int dd_ = gi - gj_; dd_ = dd_ < 0 ? -dd_ : dd_; \
    const float wI_ = same_ ? 0.f : fac; \
    const float wA_ = (same_ && dd_ <= NB_) ? fac : 0.f; \
    float v0_, v1_; \
    if (gi == gj_) { v0_ = 0.f; v1_ = 0.f; } \
    else { v0_ = 0.5f * ((AA).x + (CC).x); v1_ = 0.5f * ((AA).y + (CC).y); } \
    float s_ = v0_ + v1_, q_ = v0_ * v0_ + v1_ * v1_; \
    WREDUCE2(s_, q_); \
    const float mu_ = s_ * (1.f / DP_); \
    const float rstd_ = rsqrtf(q_ * (1.f / DP_) - mu_ * mu_ + LN_EPS_); \
    const float y0_ = (v0_ - mu_) * rstd_ * g0 + bb0; \
    const float y1_ = (v1_ - mu_) * rstd_ * g1 + bb1; \
    aI0 += wI_ * y0_; aI1 += wI_ * y1_; \
    aA0 += wA_ * y0_; aA1 += wA_ * y1_; \
    adI += wI_; adA += wA_; \
    if (wI_ != 0.f) { \
        atomicAdd(&smJI[JL][ch2], wI_ * y0_); \
        atomicAdd(&smJI[JL][ch2 + 1], wI_ * y1_); \
        if (lane == 0) atomicAdd(&smDJI[JL], wI_); \
    } \
    if (wA_ != 0.f) { \
        atomicAdd(&smJA[JL][ch2], wA_ * y0_); \
        atomicAdd(&smJA[JL][ch2 + 1], wA_ * y1_); \
        if (lane == 0) atomicAdd(&smDJA[JL], wA_); \
    } \
} while (0)

// ---------------------------------------------------------------------------
// Kernel A (role-split, 256 threads):
//  blocks [0, B*NTP):        symmetric pair tile-pass (ballot + 4-deep ILP)
//  blocks [B*NTP, +192):     seq LN+GEMM, 8 rows per block
__global__ __launch_bounds__(256) void k_main(
    const float* __restrict__ pair, const float* __restrict__ gz,
    const float* __restrict__ bz, const int* __restrict__ chain,
    const void* __restrict__ mask_raw,
    const float* __restrict__ seq, const float* __restrict__ gs,
    const float* __restrict__ bs, const float* __restrict__ Wseq,
    float* __restrict__ PI, float* __restrict__ PA,
    float* __restrict__ PDI, float* __restrict__ PDA,
    float* __restrict__ s_rows) {
    __shared__ __align__(16) float shraw[4200];   // 16.8 KB, aliased per role
    const int tid = threadIdx.x;
    const int wave = tid >> 6, lane = tid & 63;

    if (blockIdx.x < B_ * NTP_) {
        // ---------------- pair role ----------------
        float (*smJI)[DP_] = (float(*)[DP_])shraw;           // [16][128]
        float (*smJA)[DP_] = (float(*)[DP_])(shraw + 2048);  // [16][128]
        float* smDJI = shraw + 4096;                         // [16]
        float* smDJA = shraw + 4112;                         // [16]
        int* s_m = (int*)(shraw + 4128);                     // [32]
        int* s_c = (int*)(shraw + 4160);                     // [32]

        const int mode = detect_mode_block(mask_raw);

        const int b = blockIdx.x / NTP_;
        int t = blockIdx.x % NTP_;
        int ta = 0;
        while (t >= NT_ - ta) { t -= NT_ - ta; ta++; }
        const int tb = ta + t;
        const int i0 = ta * T_, j0 = tb * T_;
        const float fac = (ta == tb) ? 0.5f : 1.0f;
        const int ch2 = lane * 2;

        for (int idx = tid; idx < T_ * DP_; idx += 256) {
            (&smJI[0][0])[idx] = 0.f;
            (&smJA[0][0])[idx] = 0.f;
        }
        if (tid < T_) { smDJI[tid] = 0.f; smDJA[tid] = 0.f; }
        if (tid < 2 * T_) {
            const int loc = (tid < T_) ? (i0 + tid) : (j0 + tid - T_);
            s_m[tid] = mask_at(mask_raw, mode, b * L_ + loc);
            s_c[tid] = chain[b * L_ + loc];
        }
        __syncthreads();

        const float g0 = gz[ch2], g1 = gz[ch2 + 1];
        const float bb0 = bz[ch2], bb1 = bz[ch2 + 1];
        const float* baseb = pair + (size_t)b * L_ * L_ * DP_;

        // one ballot -> 64-bit eligibility for this wave's 4 rows x 16 cols
        unsigned long long elig;
        {
            const int r_ = lane >> 4, jl_ = lane & 15;
            const int il_ = (wave << 2) + r_;
            bool e = s_m[il_] && s_m[T_ + jl_];
            if (e) {
                const bool same = (s_c[T_ + jl_] == s_c[il_]);
                int dd = (i0 + il_) - (j0 + jl_); dd = dd < 0 ? -dd : dd;
                e = (!same) || (dd <= NB_);
            }
            elig = __ballot(e);
        }

        #pragma unroll
        for (int r = 0; r < 4; ++r) {
            const int il = (wave << 2) + r;
            const int gi = i0 + il;
            const int ci = s_c[il];
            float aI0 = 0.f, aI1 = 0.f, aA0 = 0.f, aA1 = 0.f, adI = 0.f, adA = 0.f;
            unsigned int mr = (unsigned int)((elig >> (r * 16)) & 0xFFFFull);
            while (mr) {
                int ja = __ffs(mr) - 1; mr &= mr - 1;
                int jb = -1, jc = -1, jd = -1;
                if (mr) { jb = __ffs(mr) - 1; mr &= mr - 1; }
                if (mr) { jc = __ffs(mr) - 1; mr &= mr - 1; }
                if (mr) { jd = __ffs(mr) - 1; mr &= mr - 1; }
                float2 Aa = make_float2(0.f, 0.f), Ca = Aa, Ab = Aa, Cb = Aa;
                float2 Ac = Aa, Cc = Aa, Ad = Aa, Cd = Aa;
                if (gi != j0 + ja) {
                    Aa = *(const float2*)(baseb + ((size_t)gi * L_ + (j0 + ja)) * DP_ + ch2);
                    Ca = *(const float2*)(baseb + ((size_t)(j0 + ja) * L_ + gi) * DP_ + ch2);
                }
                if (jb >= 0 && gi != j0 + jb) {
                    Ab = *(const float2*)(baseb + ((size_t)gi * L_ + (j0 + jb)) * DP_ + ch2);
                    Cb = *(const float2*)(baseb + ((size_t)(j0 + jb) * L_ + gi) * DP_ + ch2);
                }
                if (jc >= 0 && gi != j0 + jc) {
                    Ac = *(const float2*)(baseb + ((size_t)gi * L_ + (j0 + jc)) * DP_ + ch2);
                    Cc = *(const float2*)(baseb + ((size_t)(j0 + jc) * L_ + gi) * DP_ + ch2);
                }
                if (jd >= 0 && gi != j0 + jd) {
                    Ad = *(const float2*)(baseb + ((size_t)gi * L_ + (j0 + jd)) * DP_ + ch2);
                    Cd = *(const float2*)(baseb + ((size_t)(j0 + jd) * L_ + gi) * DP_ + ch2);
                }
                LNACC(ja, Aa, Ca);
                if (jb >= 0) LNACC(jb, Ab, Cb);
                if (jc >= 0) LNACC(jc, Ac, Cc);
                if (jd >= 0) LNACC(jd, Ad, Cd);
            }
            if (ta != tb) {
                const size_t o = poff(b, ta, tb, il) + ch2;
                PI[o] = aI0; PI[o + 1] = aI1;
                PA[o] = aA0; PA[o + 1] = aA1;
                if (lane == 0) {
                    PDI[pdoff(b, ta, tb, il)] = adI;
                    PDA[pdoff(b, ta, tb, il)] = adA;
                }
            } else {
                atomicAdd(&smJI[il][ch2], aI0);
                atomicAdd(&smJI[il][ch2 + 1], aI1);
                atomicAdd(&smJA[il][ch2], aA0);
                atomicAdd(&smJA[il][ch2 + 1], aA1);
                if (lane == 0) {
                    atomicAdd(&smDJI[il], adI);
                    atomicAdd(&smDJA[il], adA);
                }
            }
        }
        __syncthreads();
        // j-side (or combined diagonal) partial -> tile tb, slot ta
        for (int idx = tid; idx < T_ * DP_; idx += 256) {
            const int jl = idx >> 7, ch = idx & 127;
            const size_t o = poff(b, tb, ta, jl) + ch;
            PI[o] = smJI[jl][ch];
            PA[o] = smJA[jl][ch];
        }
        if (tid < T_) {
            PDI[pdoff(b, tb, ta, tid)] = smDJI[tid];
            PDA[pdoff(b, tb, ta, tid)] = smDJA[tid];
        }
    } else {
        // ---------------- seq role: LN + GEMM, 8 rows ----------------
        float (*xn)[DS_] = (float(*)[DS_])shraw;     // [8][384]
        float* red = shraw + 3072;                   // [2][8][4]
        const int sb = blockIdx.x - B_ * NTP_;
        const int row0 = sb * SQROWS_;
        const float gg0 = gs[tid], bv0 = bs[tid];
        float gg1 = 0.f, bv1 = 0.f;
        if (tid < 128) { gg1 = gs[256 + tid]; bv1 = bs[256 + tid]; }

        #pragma unroll
        for (int r = 0; r < SQROWS_; ++r) {
            const float* xr = seq + (size_t)(row0 + r) * DS_;
            const float x0 = xr[tid];
            const float x1 = (tid < 128) ? xr[256 + tid] : 0.f;
            float s = x0 + x1, q = x0 * x0 + x1 * x1;
            WREDUCE2(s, q);
            if (lane == 0) { red[r * 4 + wave] = s; red[32 + r * 4 + wave] = q; }
            xn[r][tid] = x0;
            if (tid < 128) xn[r][256 + tid] = x1;
        }
        __syncthreads();
        float muv[SQROWS_], rsv[SQROWS_];
        #pragma unroll
        for (int r = 0; r < SQROWS_; ++r) {
            const float ts = red[r * 4] + red[r * 4 + 1] + red[r * 4 + 2] + red[r * 4 + 3];
            const float tq = red[32 + r * 4] + red[32 + r * 4 + 1] + red[32 + r * 4 + 2] + red[32 + r * 4 + 3];
            muv[r] = ts * (1.f / DS_);
            rsv[r] = rsqrtf(tq * (1.f / DS_) - muv[r] * muv[r] + LN_EPS_);
        }
        __syncthreads();   // all raw xn written before in-place normalize reads
        #pragma unroll
        for (int r = 0; r < SQROWS_; ++r) {
            xn[r][tid] = (xn[r][tid] - muv[r]) * rsv[r] * gg0 + bv0;
            if (tid < 128) xn[r][256 + tid] = (xn[r][256 + tid] - muv[r]) * rsv[r] * gg1 + bv1;
        }
        __syncthreads();
        float acc0[SQROWS_] = {0.f, 0.f, 0.f, 0.f, 0.f, 0.f, 0.f, 0.f};
        float acc1[SQROWS_] = {0.f, 0.f, 0.f, 0.f, 0.f, 0.f, 0.f, 0.f};
        for (int k = 0; k < DS_; ++k) {
            const float w0 = Wseq[(size_t)k * DS_ + tid];
            const float w1 = (tid < 128) ? Wseq[(size_t)k * DS_ + 256 + tid] : 0.f;
            #pragma unroll
            for (int r = 0; r < SQROWS_; ++r) {
                const float xk = xn[r][k];
                acc0[r] += xk * w0;
                acc1[r] += xk * w1;
            }
        }
        #pragma unroll
        for (int r = 0; r < SQROWS_; ++r) {
            s_rows[(size_t)(row0 + r) * DS_ + tid] = acc0[r];
            if (tid < 128) s_rows[(size_t)(row0 + r) * DS_ + 256 + tid] = acc1[r];
        }
    }
}

// ---------------------------------------------------------------------------
// Kernel M (mid): role-split by blockIdx. (verified in round 5)
//  blocks [0, 96):    pair role (b,tile): reduce 24 slots -> row sums, project
//                     rows through W_pair (LDS) for peak; emit chunk partials.
//  blocks [96, 192):  seq role (b,tile): masked sum/max/count over 16 rows.
__global__ __launch_bounds__(384) void k_mid(
    const float* __restrict__ s_rows, const void* __restrict__ mask_raw,
    const float* __restrict__ Wp,
    const float* __restrict__ PI, const float* __restrict__ PA,
    const float* __restrict__ PDI, const float* __restrict__ PDA,
    float* __restrict__ psum, float* __restrict__ pmax, int* __restrict__ pcnt,
    float* __restrict__ pI, float* __restrict__ pA, float* __restrict__ pPk,
    float* __restrict__ pdI, float* __restrict__ pdA) {
    __shared__ float sWp[DP_ * DP_];   // 64 KB
    __shared__ float sRS[DP_];
    const int tid = threadIdx.x;

    if (blockIdx.x < B_ * NT_) {
        const int b = blockIdx.x / NT_, tile = blockIdx.x % NT_;
        for (int i = tid; i < DP_ * DP_; i += 384) sWp[i] = Wp[i];
        __syncthreads();
        float totI = 0.f, totA = 0.f, dI = 0.f, dA = 0.f, peak = -INFINITY;
        for (int r = 0; r < T_; ++r) {
            float dr = 0.f;
            if (tid < DP_) {
                float rsI = 0.f, rsA = 0.f, da = 0.f;
                const size_t o0 = poff(b, tile, 0, r) + tid;
                const size_t d0 = pdoff(b, tile, 0, r);
                #pragma unroll 4
                for (int s = 0; s < NT_; ++s) {
                    rsI += PI[o0 + (size_t)s * T_ * DP_];
                    rsA += PA[o0 + (size_t)s * T_ * DP_];
                    dr += PDI[d0 + (size_t)s * T_];
                    da += PDA[d0 + (size_t)s * T_];
                }
                sRS[tid] = rsI;
                totI += rsI; totA += rsA; dI += dr; dA += da;
            }
            __syncthreads();
            if (tid < DP_) {
                float acc = 0.f;
                #pragma unroll 8
                for (int k = 0; k < DP_; ++k) acc += sRS[k] * sWp[(k << 7) + tid];
                peak = fmaxf(peak, acc / fmaxf(dr, 1e-6f));
            }
            __syncthreads();
        }
        if (tid < DP_) {
            pI[(size_t)(b * NT_ + tile) * DP_ + tid] = totI;
            pA[(size_t)(b * NT_ + tile) * DP_ + tid] = totA;
            pPk[(size_t)(b * NT_ + tile) * DP_ + tid] = peak;
            if (tid == 0) { pdI[b * NT_ + tile] = dI; pdA[b * NT_ + tile] = dA; }
        }
    } else {
        const int bi = blockIdx.x - B_ * NT_;
        const int b = bi / NT_, tile = bi % NT_;
        const int mode = detect_mode_block(mask_raw);
        float sum = 0.f, mx = -INFINITY;
        int cnt = 0;
        const int l0 = tile * T_;
        for (int l = l0; l < l0 + T_; ++l) {
            if (mask_at(mask_raw, mode, b * L_ + l)) {
                float v = s_rows[(size_t)(b * L_ + l) * DS_ + tid];
                sum += v; mx = fmaxf(mx, v); cnt++;
            }
        }
        psum[(size_t)(b * NT_ + tile) * DS_ + tid] = sum;
        pmax[(size_t)(b * NT_ + tile) * DS_ + tid] = mx;
        if (tid == 0) pcnt[b * NT_ + tile] = cnt;
    }
}

// ---------------------------------------------------------------------------
// Kernel F: fused finalize per batch: combine 24 chunks, both gates, MLP head.
__global__ __launch_bounds__(384) void k_finalize(
    const float* __restrict__ psum, const float* __restrict__ pmax,
    const int* __restrict__ pcnt,
    const float* __restrict__ pI, const float* __restrict__ pA,
    const float* __restrict__ pPk,
    const float* __restrict__ pdI, const float* __restrict__ pdA,
    const float* __restrict__ Wgs, const float* __restrict__ bgs,
    const float* __restrict__ Wp, const float* __restrict__ Wgz,
    const float* __restrict__ bgz,
    const float* __restrict__ W1, const float* __restrict__ b1,
    const float* __restrict__ W2, const float* __restrict__ b2,
    float* __restrict__ out) {
    const int b = blockIdx.x;
    const int tid = threadIdx.x;
    __shared__ float sMean[DS_], sMax[DS_], fI[DP_], fA[DP_], sPk[DP_], sIM[DP_];
    __shared__ float feat[FEAT_];
    __shared__ float sdI, sdA;
    {   // seq combine
        float s = 0.f, m = -INFINITY;
        int cnt = 0;
        for (int c = 0; c < NT_; ++c) {
            s += psum[(size_t)(b * NT_ + c) * DS_ + tid];
            m = fmaxf(m, pmax[(size_t)(b * NT_ + c) * DS_ + tid]);
            cnt += pcnt[b * NT_ + c];
        }
        sMean[tid] = s / fmaxf((float)cnt, 1e-6f);
        sMax[tid] = (cnt > 0) ? m : 0.f;
    }
    if (tid < DP_) {  // pair combine
        float tI = 0.f, tA = 0.f, pk = -INFINITY, ddI = 0.f, ddA = 0.f;
        for (int c = 0; c < NT_; ++c) {
            tI += pI[(size_t)(b * NT_ + c) * DP_ + tid];
            tA += pA[(size_t)(b * NT_ + c) * DP_ + tid];
            pk = fmaxf(pk, pPk[(size_t)(b * NT_ + c) * DP_ + tid]);
            ddI += pdI[b * NT_ + c]; ddA += pdA[b * NT_ + c];
        }
        fI[tid] = tI; fA[tid] = tA; sPk[tid] = pk;
        if (tid == 0) { sdI = ddI; sdA = ddA; }
    }
    __syncthreads();
    {   // seq gate + s_feat
        float acc = bgs[tid];
        #pragma unroll 4
        for (int k = 0; k < DS_; ++k)
            acc += sMax[k] * Wgs[(size_t)k * DS_ + tid]
                 + sMean[k] * Wgs[(size_t)(k + DS_) * DS_ + tid];
        const float gate = 1.f / (1.f + expf(-acc));
        feat[tid] = sMean[tid] + gate * (sMax[tid] - sMean[tid]);
    }
    if (tid < DP_) {  // inter_mean / intra_compact projections
        float aI = 0.f, aA = 0.f;
        #pragma unroll 4
        for (int k = 0; k < DP_; ++k) {
            aI += fI[k] * Wp[(k << 7) + tid];
            aA += fA[k] * Wp[(k << 7) + tid];
        }
        sIM[tid] = aI / fmaxf(sdI, 1e-6f);
        feat[DS_ + DP_ + tid] = aA / fmaxf(sdA, 1e-6f);
    }
    __syncthreads();
    if (tid < DP_) {  // pair gate
        float acc = bgz[tid];
        #pragma unroll 4
        for (int k = 0; k < DP_; ++k)
            acc += sPk[k] * Wgz[(k << 7) + tid] + sIM[k] * Wgz[((k + DP_) << 7) + tid];
        const float gate = 1.f / (1.f + expf(-acc));
        feat[DS_ + tid] = sIM[tid] + gate * (sPk[tid] - sIM[tid]);
    }
    __syncthreads();
    if (tid < 64) {   // MLP head
        float acc = b1[tid];
        #pragma unroll 4
        for (int k = 0; k < FEAT_; ++k) acc += feat[k] * W1[(k << 6) + tid];
        float p = fmaxf(acc, 0.f) * W2[tid];
        #pragma unroll
        for (int off = 32; off; off >>= 1) p += __shfl_xor(p, off);
        if (tid == 0) out[b] = 1.f / (1.f + expf(-(p + b2[0])));
    }
}

// ---------------------------------------------------------------------------
extern "C" void kernel_launch(void* const* d_in, const int* in_sizes, int n_in,
                              void* d_out, int out_size, void* d_ws, size_t ws_size,
                              hipStream_t stream) {
    const float* seq    = (const float*)d_in[0];
    const float* pair   = (const float*)d_in[1];
    const float* ln_s_g = (const float*)d_in[2];
    const float* ln_s_b = (const float*)d_in[3];
    const float* ln_z_g = (const float*)d_in[4];
    const float* ln_z_b = (const float*)d_in[5];
    const float* W_seq  = (const float*)d_in[6];
    const float* W_pair = (const float*)d_in[7];
    const float* W_gs   = (const float*)d_in[8];
    const float* b_gs   = (const float*)d_in[9];
    const float* W_gz   = (const float*)d_in[10];
    const float* b_gz   = (const float*)d_in[11];
    const float* W1     = (const float*)d_in[12];
    const float* b1     = (const float*)d_in[13];
    const float* W2     = (const float*)d_in[14];
    const float* b2     = (const float*)d_in[15];
    const int*   chain  = (const int*)d_in[16];
    const void*  mask   = d_in[17];
    float* out = (float*)d_out;

    // workspace layout (no zero-init required: every cell written each launch)
    char* ws = (char*)d_ws;
    const size_t nP  = (size_t)B_ * NT_ * NT_ * T_ * DP_;   // 18.9 MB each
    const size_t nPD = (size_t)B_ * NT_ * NT_ * T_;
    float* PI  = (float*)ws;  ws += nP * 4;
    float* PA  = (float*)ws;  ws += nP * 4;
    float* PDI = (float*)ws;  ws += nPD * 4;
    float* PDA = (float*)ws;  ws += nPD * 4;
    float* s_rows = (float*)ws; ws += (size_t)B_ * L_ * DS_ * 4;
    float* psum = (float*)ws;   ws += (size_t)B_ * NT_ * DS_ * 4;
    float* pmax = (float*)ws;   ws += (size_t)B_ * NT_ * DS_ * 4;
    int*   pcnt = (int*)ws;     ws += (size_t)B_ * NT_ * 4;
    float* pI   = (float*)ws;   ws += (size_t)B_ * NT_ * DP_ * 4;
    float* pA   = (float*)ws;   ws += (size_t)B_ * NT_ * DP_ * 4;
    float* pPk  = (float*)ws;   ws += (size_t)B_ * NT_ * DP_ * 4;
    float* pdI  = (float*)ws;   ws += (size_t)B_ * NT_ * 4;
    float* pdA  = (float*)ws;   ws += (size_t)B_ * NT_ * 4;

    const int seqBlocks = (B_ * L_) / SQROWS_;   // 192
    k_main<<<B_ * NTP_ + seqBlocks, 256, 0, stream>>>(
        pair, ln_z_g, ln_z_b, chain, mask, seq, ln_s_g, ln_s_b, W_seq,
        PI, PA, PDI, PDA, s_rows);
    k_mid<<<2 * B_ * NT_, 384, 0, stream>>>(s_rows, mask, W_pair, PI, PA, PDI, PDA,
                                            psum, pmax, pcnt, pI, pA, pPk, pdI, pdA);
    k_finalize<<<B_, 384, 0, stream>>>(psum, pmax, pcnt, pI, pA, pPk, pdI, pdA,
                                       W_gs, b_gs, W_pair, W_gz, b_gz,
                                       W1, b1, W2, b2, out);
}